// Round 1
// baseline (1083.715 us; speedup 1.0000x reference)
//
#include <hip/hip_runtime.h>
#include <hip/hip_bf16.h>

#define BB 4
#define SS 2048
#define DD 512
#define HH 8
#define HDIM 64

typedef __attribute__((ext_vector_type(8))) short bf16x8;
typedef __attribute__((ext_vector_type(4))) float floatx4;

static __device__ __forceinline__ unsigned short f2bf(float x) {
  __hip_bfloat16 h = __float2bfloat16(x);
  unsigned short u;
  __builtin_memcpy(&u, &h, sizeof(u));
  return u;
}
static __device__ __forceinline__ float bf2f(unsigned short u) {
  union { unsigned int i; float f; } c;
  c.i = ((unsigned int)u) << 16;
  return c.f;
}

// ---------------- fp32 tiled GEMM: C = epi(A[M,K] @ W[K,N] + bias) ----------------
// 64x64 tile, BK=16, 256 threads, 4x4 per thread. M%64==0, N%64==0, K%16==0.
template<int RELU, int OUTBF16>
__global__ __launch_bounds__(256)
void gemm_bias_kernel(const float* __restrict__ A, const float* __restrict__ W,
                      const float* __restrict__ bias, float* __restrict__ C,
                      unsigned short* __restrict__ C16, int M, int N, int K)
{
  __shared__ float As[16][64];   // [k][m]
  __shared__ float Bs[16][64];   // [k][n]
  const int t  = threadIdx.x;
  const int tx = t & 15, ty = t >> 4;
  const int m0 = blockIdx.y * 64, n0 = blockIdx.x * 64;
  const int ar = t >> 2, ac = (t & 3) * 4;
  const int wr = t >> 4, wc = (t & 15) * 4;
  float acc[4][4] = {};
  for (int k0 = 0; k0 < K; k0 += 16) {
    __syncthreads();
    float4 a4 = *(const float4*)&A[(size_t)(m0 + ar) * K + k0 + ac];
    As[ac + 0][ar] = a4.x; As[ac + 1][ar] = a4.y;
    As[ac + 2][ar] = a4.z; As[ac + 3][ar] = a4.w;
    *(float4*)&Bs[wr][wc] = *(const float4*)&W[(size_t)(k0 + wr) * N + n0 + wc];
    __syncthreads();
#pragma unroll
    for (int kk = 0; kk < 16; ++kk) {
      float4 av = *(const float4*)&As[kk][ty * 4];
      float4 wv = *(const float4*)&Bs[kk][tx * 4];
      float aa[4] = {av.x, av.y, av.z, av.w};
      float ww[4] = {wv.x, wv.y, wv.z, wv.w};
#pragma unroll
      for (int i = 0; i < 4; ++i)
#pragma unroll
        for (int j = 0; j < 4; ++j)
          acc[i][j] = fmaf(aa[i], ww[j], acc[i][j]);
    }
  }
  float4 b4 = *(const float4*)&bias[n0 + tx * 4];
  float bb[4] = {b4.x, b4.y, b4.z, b4.w};
#pragma unroll
  for (int i = 0; i < 4; ++i) {
    const int m = m0 + ty * 4 + i;
    float o[4];
#pragma unroll
    for (int j = 0; j < 4; ++j) {
      float v = acc[i][j] + bb[j];
      if (RELU) v = fmaxf(v, 0.f);
      o[j] = v;
    }
    if (OUTBF16) {
      ushort4 u = make_ushort4(f2bf(o[0]), f2bf(o[1]), f2bf(o[2]), f2bf(o[3]));
      *(ushort4*)&C16[(size_t)m * N + n0 + tx * 4] = u;
    } else {
      *(float4*)&C[(size_t)m * N + n0 + tx * 4] = *(float4*)o;
    }
  }
}

// ------------- fused modulated projection: C = bf16((X@Wm + bm) * sigmoid(Lat@Wmod + bmod)) -------------
// M=8192, N=512, K1=512, K2=128
__global__ __launch_bounds__(256)
void gemm_mod_kernel(const float* __restrict__ X, const float* __restrict__ Wm,
                     const float* __restrict__ bm, const float* __restrict__ Lat,
                     const float* __restrict__ Wmod, const float* __restrict__ bmod,
                     unsigned short* __restrict__ C16)
{
  __shared__ float As[16][64];
  __shared__ float Bs[16][64];
  const int t  = threadIdx.x;
  const int tx = t & 15, ty = t >> 4;
  const int m0 = blockIdx.y * 64, n0 = blockIdx.x * 64;
  const int ar = t >> 2, ac = (t & 3) * 4;
  const int wr = t >> 4, wc = (t & 15) * 4;
  float acc1[4][4] = {};
  for (int k0 = 0; k0 < 512; k0 += 16) {
    __syncthreads();
    float4 a4 = *(const float4*)&X[(size_t)(m0 + ar) * 512 + k0 + ac];
    As[ac + 0][ar] = a4.x; As[ac + 1][ar] = a4.y;
    As[ac + 2][ar] = a4.z; As[ac + 3][ar] = a4.w;
    *(float4*)&Bs[wr][wc] = *(const float4*)&Wm[(size_t)(k0 + wr) * 512 + n0 + wc];
    __syncthreads();
#pragma unroll
    for (int kk = 0; kk < 16; ++kk) {
      float4 av = *(const float4*)&As[kk][ty * 4];
      float4 wv = *(const float4*)&Bs[kk][tx * 4];
      float aa[4] = {av.x, av.y, av.z, av.w};
      float ww[4] = {wv.x, wv.y, wv.z, wv.w};
#pragma unroll
      for (int i = 0; i < 4; ++i)
#pragma unroll
        for (int j = 0; j < 4; ++j)
          acc1[i][j] = fmaf(aa[i], ww[j], acc1[i][j]);
    }
  }
  float acc2[4][4] = {};
  for (int k0 = 0; k0 < 128; k0 += 16) {
    __syncthreads();
    float4 a4 = *(const float4*)&Lat[(size_t)(m0 + ar) * 128 + k0 + ac];
    As[ac + 0][ar] = a4.x; As[ac + 1][ar] = a4.y;
    As[ac + 2][ar] = a4.z; As[ac + 3][ar] = a4.w;
    *(float4*)&Bs[wr][wc] = *(const float4*)&Wmod[(size_t)(k0 + wr) * 512 + n0 + wc];
    __syncthreads();
#pragma unroll
    for (int kk = 0; kk < 16; ++kk) {
      float4 av = *(const float4*)&As[kk][ty * 4];
      float4 wv = *(const float4*)&Bs[kk][tx * 4];
      float aa[4] = {av.x, av.y, av.z, av.w};
      float ww[4] = {wv.x, wv.y, wv.z, wv.w};
#pragma unroll
      for (int i = 0; i < 4; ++i)
#pragma unroll
        for (int j = 0; j < 4; ++j)
          acc2[i][j] = fmaf(aa[i], ww[j], acc2[i][j]);
    }
  }
  float4 b14 = *(const float4*)&bm[n0 + tx * 4];
  float4 b24 = *(const float4*)&bmod[n0 + tx * 4];
  float bb1[4] = {b14.x, b14.y, b14.z, b14.w};
  float bb2[4] = {b24.x, b24.y, b24.z, b24.w};
#pragma unroll
  for (int i = 0; i < 4; ++i) {
    const int m = m0 + ty * 4 + i;
    unsigned short uu[4];
#pragma unroll
    for (int j = 0; j < 4; ++j) {
      float v1 = acc1[i][j] + bb1[j];
      float v2 = acc2[i][j] + bb2[j];
      float q  = v1 / (1.f + __expf(-v2));   // v1 * sigmoid(v2)
      uu[j] = f2bf(q);
    }
    ushort4 u = make_ushort4(uu[0], uu[1], uu[2], uu[3]);
    *(ushort4*)&C16[(size_t)m * 512 + n0 + tx * 4] = u;
  }
}

// ------------- V transpose: bf16 [B*S, D] -> bf16 [B, H, HD, S] -------------
__global__ __launch_bounds__(256)
void vtrans_kernel(const unsigned short* __restrict__ V16, unsigned short* __restrict__ Vt)
{
  __shared__ unsigned short T[64][72];   // padded to dodge worst bank patterns
  const int x  = blockIdx.x;             // grid = B*H*(S/64) = 1024
  const int st = x & 31;
  const int h  = (x >> 5) & 7;
  const int b  = x >> 8;
  const int t  = threadIdx.x;
  const unsigned short* src = V16 + ((size_t)b * SS + st * 64) * DD + h * HDIM;
  for (int i = t; i < 1024; i += 256) {
    int r = i >> 4, c4 = (i & 15) * 4;
    *(ushort4*)&T[r][c4] = *(const ushort4*)&src[(size_t)r * DD + c4];
  }
  __syncthreads();
  unsigned short* dst = Vt + ((size_t)(b * HH + h) * HDIM) * SS + st * 64;
  for (int i = t; i < 1024; i += 256) {
    int hd = i >> 4, s4 = (i & 15) * 4;
    ushort4 u = make_ushort4(T[s4 + 0][hd], T[s4 + 1][hd], T[s4 + 2][hd], T[s4 + 3][hd]);
    *(ushort4*)&dst[(size_t)hd * SS + s4] = u;
  }
}

// ------------- two-pass flash attention with bf16 MFMA -------------
// grid = B*H*(S/64) = 1024 blocks, 256 threads (4 waves x 16 q-rows each).
__global__ __launch_bounds__(256)
void attn_kernel(const unsigned short* __restrict__ Q16,
                 const unsigned short* __restrict__ K16,
                 const unsigned short* __restrict__ Vt,
                 float* __restrict__ AW, float* __restrict__ AO)
{
  __shared__ alignas(16) unsigned short Qs[64][64];        // [q_local][d]
  __shared__ alignas(16) unsigned short Ks[64][64];        // [key][d]
  __shared__ alignas(16) unsigned short Vs[64][64];        // [hd][key]  (V^T tile)
  __shared__ alignas(16) unsigned short Ps[4][16][64];     // per-wave weights [q][key]

  const int t    = threadIdx.x;
  const int wid  = t >> 6;
  const int lane = t & 63;
  const int quad = lane >> 4;
  const int l16  = lane & 15;
  const int x  = blockIdx.x;
  const int qb = x & 31;
  const int h  = (x >> 5) & 7;
  const int b  = x >> 8;
  const int q0 = qb * 64;
  const float scale = 0.125f;   // 1/sqrt(64)

  // stage Q tile (bf16)
  const unsigned short* Qg = Q16 + ((size_t)b * SS + q0) * DD + h * HDIM;
  for (int i = t; i < 1024; i += 256) {
    int r = i >> 4, c4 = (i & 15) * 4;
    *(ushort4*)&Qs[r][c4] = *(const ushort4*)&Qg[(size_t)r * DD + c4];
  }
  __syncthreads();
  // A fragments: A[m=l16][k=quad*8+j]  (k = d)
  const bf16x8 a0 = *(const bf16x8*)&Qs[wid * 16 + l16][quad * 8];
  const bf16x8 a1 = *(const bf16x8*)&Qs[wid * 16 + l16][32 + quad * 8];

  const unsigned short* Kg = K16 + (size_t)b * SS * DD + h * HDIM;
  const unsigned short* Vg = Vt + ((size_t)(b * HH + h) * HDIM) * SS;

  float m_run[4] = {-1e30f, -1e30f, -1e30f, -1e30f};
  float l_run[4] = {0.f, 0.f, 0.f, 0.f};

  // ---- Pass A: online (m, l) over all keys ----
  for (int kt = 0; kt < SS / 64; ++kt) {
    __syncthreads();
    for (int i = t; i < 1024; i += 256) {
      int r = i >> 4, c4 = (i & 15) * 4;
      *(ushort4*)&Ks[r][c4] = *(const ushort4*)&Kg[(size_t)(kt * 64 + r) * DD + c4];
    }
    __syncthreads();
    float s[4][4];
#pragma unroll
    for (int kst = 0; kst < 4; ++kst) {
      bf16x8 bb0 = *(const bf16x8*)&Ks[kst * 16 + l16][quad * 8];
      bf16x8 bb1 = *(const bf16x8*)&Ks[kst * 16 + l16][32 + quad * 8];
      floatx4 cc = {0.f, 0.f, 0.f, 0.f};
      cc = __builtin_amdgcn_mfma_f32_16x16x32_bf16(a0, bb0, cc, 0, 0, 0);
      cc = __builtin_amdgcn_mfma_f32_16x16x32_bf16(a1, bb1, cc, 0, 0, 0);
#pragma unroll
      for (int r = 0; r < 4; ++r) s[kst][r] = cc[r] * scale;
    }
#pragma unroll
    for (int r = 0; r < 4; ++r) {
      float mt = fmaxf(fmaxf(s[0][r], s[1][r]), fmaxf(s[2][r], s[3][r]));
#pragma unroll
      for (int off = 1; off < 16; off <<= 1)
        mt = fmaxf(mt, __shfl_xor(mt, off, 64));
      float nm = fmaxf(m_run[r], mt);
      float su = __expf(s[0][r] - nm) + __expf(s[1][r] - nm) +
                 __expf(s[2][r] - nm) + __expf(s[3][r] - nm);
#pragma unroll
      for (int off = 1; off < 16; off <<= 1)
        su += __shfl_xor(su, off, 64);
      l_run[r] = l_run[r] * __expf(m_run[r] - nm) + su;
      m_run[r] = nm;
    }
  }
  float inv_l[4];
#pragma unroll
  for (int r = 0; r < 4; ++r) inv_l[r] = 1.f / l_run[r];

  floatx4 o[4];
#pragma unroll
  for (int n = 0; n < 4; ++n) { floatx4 z = {0.f, 0.f, 0.f, 0.f}; o[n] = z; }

  const size_t awb = ((size_t)(b * HH + h) * SS + q0 + wid * 16) * SS;

  // ---- Pass B: recompute scores, write normalized weights, accumulate PV ----
  for (int kt = 0; kt < SS / 64; ++kt) {
    __syncthreads();
    for (int i = t; i < 1024; i += 256) {
      int r = i >> 4, c4 = (i & 15) * 4;
      *(ushort4*)&Ks[r][c4] = *(const ushort4*)&Kg[(size_t)(kt * 64 + r) * DD + c4];
      *(ushort4*)&Vs[r][c4] = *(const ushort4*)&Vg[(size_t)r * SS + kt * 64 + c4];
    }
    __syncthreads();
#pragma unroll
    for (int kst = 0; kst < 4; ++kst) {
      bf16x8 bb0 = *(const bf16x8*)&Ks[kst * 16 + l16][quad * 8];
      bf16x8 bb1 = *(const bf16x8*)&Ks[kst * 16 + l16][32 + quad * 8];
      floatx4 cc = {0.f, 0.f, 0.f, 0.f};
      cc = __builtin_amdgcn_mfma_f32_16x16x32_bf16(a0, bb0, cc, 0, 0, 0);
      cc = __builtin_amdgcn_mfma_f32_16x16x32_bf16(a1, bb1, cc, 0, 0, 0);
#pragma unroll
      for (int r = 0; r < 4; ++r) {
        float wv = __expf(cc[r] * scale - m_run[r]) * inv_l[r];
        Ps[wid][quad * 4 + r][kst * 16 + l16] = f2bf(wv);
      }
    }
    __syncthreads();   // make Ps visible (also drains LDS writes)
    // coalesced fp32 weight write for this wave's 16 rows x 64 keys
    for (int i = lane; i < 256; i += 64) {
      int q = i >> 4, k4 = (i & 15) * 4;
      ushort4 u = *(const ushort4*)&Ps[wid][q][k4];
      float4 f = make_float4(bf2f(u.x), bf2f(u.y), bf2f(u.z), bf2f(u.w));
      *(float4*)&AW[awb + (size_t)q * SS + kt * 64 + k4] = f;
    }
    // PV: A = P[q][key] (LDS round-trip), B = V^T[hd][key]
#pragma unroll
    for (int c2 = 0; c2 < 2; ++c2) {
      bf16x8 ap = *(const bf16x8*)&Ps[wid][l16][c2 * 32 + quad * 8];
#pragma unroll
      for (int n = 0; n < 4; ++n) {
        bf16x8 bv = *(const bf16x8*)&Vs[n * 16 + l16][c2 * 32 + quad * 8];
        o[n] = __builtin_amdgcn_mfma_f32_16x16x32_bf16(ap, bv, o[n], 0, 0, 0);
      }
    }
  }
  // write attention output (fp32): C-layout row=quad*4+reg, col=n*16+l16
  float* AOg = AO + ((size_t)b * SS + q0 + wid * 16) * DD + h * HDIM;
#pragma unroll
  for (int n = 0; n < 4; ++n)
#pragma unroll
    for (int r = 0; r < 4; ++r)
      AOg[(size_t)(quad * 4 + r) * DD + n * 16 + l16] = o[n][r];
}

extern "C" void kernel_launch(void* const* d_in, const int* in_sizes, int n_in,
                              void* d_out, int out_size, void* d_ws, size_t ws_size,
                              hipStream_t stream) {
  (void)in_sizes; (void)n_in; (void)out_size; (void)ws_size;
  const float* query = (const float*)d_in[0];
  const float* key_i = (const float*)d_in[1];
  const float* value = (const float*)d_in[2];
  const float* Wq  = (const float*)d_in[3];
  const float* bq  = (const float*)d_in[4];
  const float* Wk  = (const float*)d_in[5];
  const float* bk  = (const float*)d_in[6];
  const float* Wv  = (const float*)d_in[7];
  const float* bv  = (const float*)d_in[8];
  const float* Wo  = (const float*)d_in[9];
  const float* bo  = (const float*)d_in[10];
  const float* Wg  = (const float*)d_in[11];
  const float* bg  = (const float*)d_in[12];
  const float* Wmq = (const float*)d_in[13];
  const float* bmq = (const float*)d_in[14];
  const float* Wmk = (const float*)d_in[15];
  const float* bmk = (const float*)d_in[16];

  float* out = (float*)d_out;
  float* AW  = out + (size_t)BB * SS * DD;          // attn_weights at offset 4,194,304

  char* ws = (char*)d_ws;
  float*          lat = (float*)ws;                               //  4 MiB: latent [8192,128] fp32
  unsigned short* q16 = (unsigned short*)(ws + (4u  << 20));      //  8 MiB: q bf16 [8192,512]
  unsigned short* k16 = (unsigned short*)(ws + (12u << 20));      //  8 MiB
  unsigned short* v16 = (unsigned short*)(ws + (20u << 20));      //  8 MiB
  unsigned short* vt  = (unsigned short*)(ws + (28u << 20));      //  8 MiB: V^T bf16 [B,H,64,2048]
  float*          ao  = (float*)(ws + (36u << 20));               // 16 MiB: attn_out fp32 [8192,512]

  dim3 blk(256);
  // 1. latent = relu(query @ Wg + bg)
  gemm_bias_kernel<1, 0><<<dim3(128 / 64, 8192 / 64), blk, 0, stream>>>(
      query, Wg, bg, lat, nullptr, 8192, 128, 512);
  // 2. q = bf16((query @ Wq + bq) * sigmoid(latent @ Wmq + bmq))
  gemm_mod_kernel<<<dim3(512 / 64, 8192 / 64), blk, 0, stream>>>(
      query, Wq, bq, lat, Wmq, bmq, q16);
  // 3. k = bf16((key @ Wk + bk) * sigmoid(latent @ Wmk + bmk))
  gemm_mod_kernel<<<dim3(512 / 64, 8192 / 64), blk, 0, stream>>>(
      key_i, Wk, bk, lat, Wmk, bmk, k16);
  // 4. v = bf16(value @ Wv + bv)
  gemm_bias_kernel<0, 1><<<dim3(512 / 64, 8192 / 64), blk, 0, stream>>>(
      value, Wv, bv, nullptr, v16, 8192, 512, 512);
  // 5. V^T per (b,h)
  vtrans_kernel<<<dim3(1024), blk, 0, stream>>>(v16, vt);
  // 6. attention: weights -> d_out tail, attn_out -> ws
  attn_kernel<<<dim3(1024), blk, 0, stream>>>(q16, k16, vt, AW, ao);
  // 7. output = attn_out @ Wo + bo
  gemm_bias_kernel<0, 0><<<dim3(512 / 64, 8192 / 64), blk, 0, stream>>>(
      ao, Wo, bo, out, nullptr, 8192, 512, 512);
}